// Round 1
// baseline (475.824 us; speedup 1.0000x reference)
//
#include <hip/hip_runtime.h>
#include <math.h>

#define HDIM 1024
#define LDIM 128
#define VDIM 50257

__device__ __forceinline__ float dot4(float4 a, float4 b) {
    return a.x * b.x + a.y * b.y + a.z * b.z + a.w * b.w;
}

__device__ __forceinline__ float wave_reduce_sum(float v) {
#pragma unroll
    for (int off = 32; off > 0; off >>= 1) v += __shfl_down(v, off, 64);
    return v;
}

// ---------------------------------------------------------------------------
// 1) attn_logits[l] = dot(concat(emb[id], h0), attn_w[l]) + attn_b[l]
//    grid = 128 blocks (one per l), block = 256 threads (float4: 2048 = 2*256*4)
__global__ void k_attn_logits(const int* __restrict__ idx,
                              const float* __restrict__ hidden,
                              const float* __restrict__ emb,
                              const float* __restrict__ attn_w,
                              const float* __restrict__ attn_b,
                              float* __restrict__ logits) {
    __shared__ float sm[4];
    int l = blockIdx.x, t = threadIdx.x;
    long id = (long)idx[0];
    const float4* row = (const float4*)(attn_w + (size_t)l * (2 * HDIM));
    const float4* er  = (const float4*)(emb + (size_t)id * HDIM);
    const float4* hr  = (const float4*)hidden;  // hidden[0]
    float acc = dot4(row[t], er[t]) + dot4(row[256 + t], hr[t]);
    acc = wave_reduce_sum(acc);
    int wave = t >> 6, lane = t & 63;
    if (lane == 0) sm[wave] = acc;
    __syncthreads();
    if (t == 0) logits[l] = sm[0] + sm[1] + sm[2] + sm[3] + attn_b[l];
}

// ---------------------------------------------------------------------------
// 2) softmax over 128 logits -> attn_weights (written to d_out region)
//    1 block, 128 threads
__global__ void k_softmax128(const float* __restrict__ logits,
                             float* __restrict__ attnw_out) {
    __shared__ float sm[128];
    int t = threadIdx.x;
    float v = logits[t];
    sm[t] = v;
    __syncthreads();
    for (int s = 64; s > 0; s >>= 1) {
        if (t < s) sm[t] = fmaxf(sm[t], sm[t + s]);
        __syncthreads();
    }
    float m = sm[0];
    __syncthreads();
    float e = expf(v - m);
    sm[t] = e;
    __syncthreads();
    for (int s = 64; s > 0; s >>= 1) {
        if (t < s) sm[t] += sm[t + s];
        __syncthreads();
    }
    attnw_out[t] = e / sm[0];
}

// ---------------------------------------------------------------------------
// 3) attn_applied[h] = sum_l w[l] * enc[l*H + h]   (coalesced over h)
//    grid = 4 blocks * 256 threads
__global__ void k_attn_applied(const float* __restrict__ w,
                               const float* __restrict__ enc,
                               float* __restrict__ applied) {
    __shared__ float sw[LDIM];
    int t = threadIdx.x;
    if (t < LDIM) sw[t] = w[t];
    __syncthreads();
    int h = blockIdx.x * 256 + t;
    float acc = 0.f;
#pragma unroll 4
    for (int l = 0; l < LDIM; ++l) acc += sw[l] * enc[(size_t)l * HDIM + h];
    applied[h] = acc;
}

// ---------------------------------------------------------------------------
// 4) x[i] = relu(dot(concat(emb[id], applied), comb_w[i]) + comb_b[i])
//    grid = 1024 blocks, block = 256
__global__ void k_combine(const int* __restrict__ idx,
                          const float* __restrict__ emb,
                          const float* __restrict__ applied,
                          const float* __restrict__ comb_w,
                          const float* __restrict__ comb_b,
                          float* __restrict__ x) {
    __shared__ float sm[4];
    int i = blockIdx.x, t = threadIdx.x;
    long id = (long)idx[0];
    const float4* row = (const float4*)(comb_w + (size_t)i * (2 * HDIM));
    const float4* er  = (const float4*)(emb + (size_t)id * HDIM);
    const float4* ap  = (const float4*)applied;
    float acc = dot4(row[t], er[t]) + dot4(row[256 + t], ap[t]);
    acc = wave_reduce_sum(acc);
    int wave = t >> 6, lane = t & 63;
    if (lane == 0) sm[wave] = acc;
    __syncthreads();
    if (t == 0) {
        float v = sm[0] + sm[1] + sm[2] + sm[3] + comb_b[i];
        x[i] = v > 0.f ? v : 0.f;
    }
}

// ---------------------------------------------------------------------------
// 5) fused GRU cell: one block per output j, 6 dots of length 1024
//    (each thread: exactly one float4 per row)
__global__ void k_gru(const float* __restrict__ x, const float* __restrict__ h,
                      const float* __restrict__ w_ih, const float* __restrict__ w_hh,
                      const float* __restrict__ b_ih, const float* __restrict__ b_hh,
                      float* __restrict__ h_new) {
    __shared__ float red[6][4];
    int j = blockIdx.x, t = threadIdx.x;
    const float4 xv = ((const float4*)x)[t];
    const float4 hv = ((const float4*)h)[t];
    const float4* wir = (const float4*)(w_ih + (size_t)j * HDIM);
    const float4* wiz = (const float4*)(w_ih + (size_t)(HDIM + j) * HDIM);
    const float4* win = (const float4*)(w_ih + (size_t)(2 * HDIM + j) * HDIM);
    const float4* whr = (const float4*)(w_hh + (size_t)j * HDIM);
    const float4* whz = (const float4*)(w_hh + (size_t)(HDIM + j) * HDIM);
    const float4* whn = (const float4*)(w_hh + (size_t)(2 * HDIM + j) * HDIM);
    float v0 = dot4(wir[t], xv);
    float v1 = dot4(wiz[t], xv);
    float v2 = dot4(win[t], xv);
    float v3 = dot4(whr[t], hv);
    float v4 = dot4(whz[t], hv);
    float v5 = dot4(whn[t], hv);
    v0 = wave_reduce_sum(v0);
    v1 = wave_reduce_sum(v1);
    v2 = wave_reduce_sum(v2);
    v3 = wave_reduce_sum(v3);
    v4 = wave_reduce_sum(v4);
    v5 = wave_reduce_sum(v5);
    int wave = t >> 6, lane = t & 63;
    if (lane == 0) {
        red[0][wave] = v0; red[1][wave] = v1; red[2][wave] = v2;
        red[3][wave] = v3; red[4][wave] = v4; red[5][wave] = v5;
    }
    __syncthreads();
    if (t == 0) {
        float ir  = red[0][0] + red[0][1] + red[0][2] + red[0][3] + b_ih[j];
        float iz  = red[1][0] + red[1][1] + red[1][2] + red[1][3] + b_ih[HDIM + j];
        float in_ = red[2][0] + red[2][1] + red[2][2] + red[2][3] + b_ih[2 * HDIM + j];
        float hr_ = red[3][0] + red[3][1] + red[3][2] + red[3][3] + b_hh[j];
        float hz  = red[4][0] + red[4][1] + red[4][2] + red[4][3] + b_hh[HDIM + j];
        float hn  = red[5][0] + red[5][1] + red[5][2] + red[5][3] + b_hh[2 * HDIM + j];
        float r = 1.f / (1.f + expf(-(ir + hr_)));
        float z = 1.f / (1.f + expf(-(iz + hz)));
        float n = tanhf(in_ + r * hn);
        h_new[j] = (1.f - z) * n + z * h[j];
    }
}

// ---------------------------------------------------------------------------
// 7) logits[r] = dot(h1, out_w[r]) + out_b[r]; one wave per row, h1 in LDS
//    grid = ceil(V/4) blocks, block = 256 (4 waves)
__global__ void k_out_logits(const float* __restrict__ h1,
                             const float* __restrict__ out_w,
                             const float* __restrict__ out_b,
                             float* __restrict__ logits) {
    __shared__ float hs[HDIM];
    int t = threadIdx.x;
    ((float4*)hs)[t] = ((const float4*)h1)[t];
    __syncthreads();
    int wave = t >> 6, lane = t & 63;
    int r = blockIdx.x * 4 + wave;
    if (r >= VDIM) return;
    const float4* row = (const float4*)(out_w + (size_t)r * HDIM);
    const float4* hv  = (const float4*)hs;
    float acc = 0.f;
#pragma unroll
    for (int it = 0; it < 4; ++it) {
        acc += dot4(row[it * 64 + lane], hv[it * 64 + lane]);
    }
    acc = wave_reduce_sum(acc);
    if (lane == 0) logits[r] = acc + out_b[r];
}

// ---------------------------------------------------------------------------
// 8) per-block online (max, sumexp) over logits
__global__ void k_lse_partial(const float* __restrict__ logits, int n,
                              float2* __restrict__ pairs) {
    __shared__ float2 sp[4];
    float m = -INFINITY, s = 0.f;
    for (int i = blockIdx.x * blockDim.x + threadIdx.x; i < n;
         i += gridDim.x * blockDim.x) {
        float v = logits[i];
        if (v > m) { s = s * expf(m - v) + 1.f; m = v; }
        else       { s += expf(v - m); }
    }
#pragma unroll
    for (int off = 32; off > 0; off >>= 1) {
        float om = __shfl_down(m, off, 64);
        float os = __shfl_down(s, off, 64);
        float M = fmaxf(m, om);
        float sn = 0.f;
        if (m > -INFINITY)  sn += s * expf(m - M);
        if (om > -INFINITY) sn += os * expf(om - M);
        m = M; s = sn;
    }
    int wave = threadIdx.x >> 6, lane = threadIdx.x & 63;
    if (lane == 0) sp[wave] = make_float2(m, s);
    __syncthreads();
    if (threadIdx.x == 0) {
        float M = -INFINITY, S = 0.f;
        for (int i = 0; i < 4; ++i) {
            float mm = sp[i].x, ss = sp[i].y;
            float M2 = fmaxf(M, mm);
            float S2 = 0.f;
            if (M > -INFINITY)  S2 += S * expf(M - M2);
            if (mm > -INFINITY) S2 += ss * expf(mm - M2);
            M = M2; S = S2;
        }
        pairs[blockIdx.x] = make_float2(M, S);
    }
}

// ---------------------------------------------------------------------------
// 9) in-place log-softmax finish: out[i] -= (M + log(S))
__global__ void k_logsoftmax_final(float* __restrict__ logits,
                                   const float2* __restrict__ pairs, int npairs,
                                   int n) {
    __shared__ float corr;
    if (threadIdx.x == 0) {
        float M = -INFINITY, S = 0.f;
        for (int i = 0; i < npairs; ++i) {
            float mm = pairs[i].x, ss = pairs[i].y;
            float M2 = fmaxf(M, mm);
            float S2 = 0.f;
            if (M > -INFINITY)  S2 += S * expf(M - M2);
            if (mm > -INFINITY) S2 += ss * expf(mm - M2);
            M = M2; S = S2;
        }
        corr = M + logf(S);
    }
    __syncthreads();
    float c = corr;
    for (int i = blockIdx.x * blockDim.x + threadIdx.x; i < n;
         i += gridDim.x * blockDim.x) {
        logits[i] -= c;
    }
}

// ---------------------------------------------------------------------------
extern "C" void kernel_launch(void* const* d_in, const int* in_sizes, int n_in,
                              void* d_out, int out_size, void* d_ws, size_t ws_size,
                              hipStream_t stream) {
    const int*   idx     = (const int*)d_in[0];
    const float* hidden  = (const float*)d_in[1];   // (2,1,1024)
    const float* enc     = (const float*)d_in[2];   // (128,1024)
    const float* emb     = (const float*)d_in[3];   // (50257,1024)
    const float* attn_w  = (const float*)d_in[4];   // (128,2048)
    const float* attn_b  = (const float*)d_in[5];   // (128,)
    const float* comb_w  = (const float*)d_in[6];   // (1024,2048)
    const float* comb_b  = (const float*)d_in[7];   // (1024,)
    const float* w_ih0   = (const float*)d_in[8];
    const float* w_hh0   = (const float*)d_in[9];
    const float* b_ih0   = (const float*)d_in[10];
    const float* b_hh0   = (const float*)d_in[11];
    const float* w_ih1   = (const float*)d_in[12];
    const float* w_hh1   = (const float*)d_in[13];
    const float* b_ih1   = (const float*)d_in[14];
    const float* b_hh1   = (const float*)d_in[15];
    const float* out_w   = (const float*)d_in[16];  // (50257,1024)
    const float* out_b   = (const float*)d_in[17];  // (50257,)

    float* out = (float*)d_out;
    // output layout: [log_softmax V | h0 H | h1 H | attn_weights L]
    float* out_logp  = out;
    float* out_h0    = out + VDIM;
    float* out_h1    = out + VDIM + HDIM;
    float* out_attnw = out + VDIM + 2 * HDIM;

    float* ws = (float*)d_ws;
    float*  ws_alog  = ws;            // 128
    float*  ws_appl  = ws + 128;      // 1024
    float*  ws_x     = ws + 1152;     // 1024
    float2* ws_pairs = (float2*)(ws + 2176);  // 128 float2

    k_attn_logits<<<LDIM, 256, 0, stream>>>(idx, hidden, emb, attn_w, attn_b, ws_alog);
    k_softmax128<<<1, 128, 0, stream>>>(ws_alog, out_attnw);
    k_attn_applied<<<HDIM / 256, 256, 0, stream>>>(out_attnw, enc, ws_appl);
    k_combine<<<HDIM, 256, 0, stream>>>(idx, emb, ws_appl, comb_w, comb_b, ws_x);
    k_gru<<<HDIM, 256, 0, stream>>>(ws_x, hidden, w_ih0, w_hh0, b_ih0, b_hh0, out_h0);
    k_gru<<<HDIM, 256, 0, stream>>>(out_h0, hidden + HDIM, w_ih1, w_hh1, b_ih1, b_hh1, out_h1);
    k_out_logits<<<(VDIM + 3) / 4, 256, 0, stream>>>(out_h1, out_w, out_b, out_logp);
    k_lse_partial<<<128, 256, 0, stream>>>(out_logp, VDIM, ws_pairs);
    k_logsoftmax_final<<<128, 256, 0, stream>>>(out_logp, ws_pairs, 128, VDIM);
}